// Round 8
// baseline (610.993 us; speedup 1.0000x reference)
//
#include <hip/hip_runtime.h>
#include <math.h>

// ---------- model constants ----------
#define NUM_GRAPHS 1024
#define NPG 9
#define NN 9216            // nodes
#define NN2 18432          // batched stage-1 rows (low|high)
#define POSD 64

typedef __attribute__((ext_vector_type(8))) short bf16x8;
typedef __attribute__((ext_vector_type(4))) float f32x4;

__device__ __forceinline__ float gelu_f(float x) {
    return 0.5f * x * (1.0f + erff(x * 0.70710678118654752f));
}
// fast gelu (tanh form), |err| <= ~3e-3 vs erf-gelu (edge aggregation only)
__device__ __forceinline__ float gelu_fast(float x) {
    float y = 0.7978845608f * x * (1.0f + 0.044715f * x * x);
    float t = __expf(-2.0f * fabsf(y));
    float r = (1.0f - t) / (1.0f + t);
    r = copysignf(r, y);
    return 0.5f * x * (1.0f + r);
}
__device__ __forceinline__ ushort f2b(float v) {
    unsigned u = __float_as_uint(v);
    return (ushort)((u + 0x7fffu + ((u >> 16) & 1u)) >> 16);
}
__device__ __forceinline__ float b2f(ushort u) {
    return __uint_as_float(((unsigned)u) << 16);
}
__device__ __forceinline__ void gload16(const ushort* g, ushort* l) {
    __builtin_amdgcn_global_load_lds((const __attribute__((address_space(1))) void*)g,
                                     (__attribute__((address_space(3))) void*)l, 16, 0, 0);
}

// ---------------------------------------------------------------------------
// bf16 MFMA GEMM, 3-stage software pipeline (prefetch distance 2) with
// partial-drain barriers: s_waitcnt vmcnt(4) keeps the next stage's loads in
// flight across s_barrier (AITER-style; __syncthreads would drain vmcnt(0)).
// C[M,N] = A[M,K@z]bf16 @ Wt[N,K@z]^T + bias1[n] + prow[(m%9)*ldp + n]
// Tile 128x128, 4 waves, BK=32. outF gets per-chunk partials (+z*partStride).
// ---------------------------------------------------------------------------
__global__ __launch_bounds__(256, 3) void mgemm(
    const ushort* __restrict__ A, int lda,
    const ushort* __restrict__ Wt, int ldw,
    const float* __restrict__ bias1,
    const float* __restrict__ prow, int ldp,
    float* outF, ushort* outB, int ldo,
    long partStride, int K)
{
    __shared__ ushort sA[3][128 * 32];
    __shared__ ushort sB[3][128 * 32];
    const int wv = threadIdx.x >> 6, lane = threadIdx.x & 63;
    const int rh = wv & 1, ch = wv >> 1;
    const int m0 = blockIdx.y * 128, n0 = blockIdx.x * 128;
    const int koff = blockIdx.z * K;

    f32x4 acc[4][4];
#pragma unroll
    for (int i = 0; i < 4; i++)
#pragma unroll
        for (int j = 0; j < 4; j++) acc[i][j] = (f32x4){0.f, 0.f, 0.f, 0.f};

    const ushort* Ab = A + (size_t)m0 * lda + koff;
    const ushort* Wb = Wt + (size_t)n0 * ldw + koff;
    if (outF) outF += (size_t)blockIdx.z * partStride;

    // stage: 4 global_load_lds per wave (2 A-chunks + 2 B-chunks of 1KB)
    auto stage = [&](int b, int k0) {
#pragma unroll
        for (int i = 0; i < 2; i++) {
            int c = wv * 2 + i;
            int u = c * 64 + lane;
            int row = u >> 2, p = u & 3;
            int q = (p - (row >> 1)) & 3;
            gload16(Ab + (size_t)row * lda + k0 + q * 8, sA[b] + c * 512);
            gload16(Wb + (size_t)row * ldw + k0 + q * 8, sB[b] + c * 512);
        }
    };

    const int nsteps = K >> 5;
    stage(0, 0);
    stage(1, 32);
    int buf = 0;
    for (int s = 0; s < nsteps; s++) {
        if (s + 2 < nsteps) {
            // wait only for the oldest stage's 4 loads; keep next stage in flight
            asm volatile("s_waitcnt vmcnt(4)\n\ts_barrier" ::: "memory");
            int nb = buf + 2; if (nb >= 3) nb -= 3;
            stage(nb, (s + 2) << 5);
        } else {
            asm volatile("s_waitcnt vmcnt(0)\n\ts_barrier" ::: "memory");
        }
        const int qg = lane >> 4;
        bf16x8 af[4], bfr[4];
#pragma unroll
        for (int bi = 0; bi < 4; bi++) {
            int r = rh * 64 + bi * 16 + (lane & 15);
            af[bi] = *(const bf16x8*)(sA[buf] + (r * 4 + ((qg + (r >> 1)) & 3)) * 8);
        }
#pragma unroll
        for (int bj = 0; bj < 4; bj++) {
            int r = ch * 64 + bj * 16 + (lane & 15);
            bfr[bj] = *(const bf16x8*)(sB[buf] + (r * 4 + ((qg + (r >> 1)) & 3)) * 8);
        }
#pragma unroll
        for (int bi = 0; bi < 4; bi++)
#pragma unroll
            for (int bj = 0; bj < 4; bj++)
                acc[bi][bj] = __builtin_amdgcn_mfma_f32_16x16x32_bf16(
                    af[bi], bfr[bj], acc[bi][bj], 0, 0, 0);
        if (++buf >= 3) buf = 0;
    }

#pragma unroll
    for (int bi = 0; bi < 4; bi++) {
#pragma unroll
        for (int r = 0; r < 4; r++) {
            int m = m0 + rh * 64 + bi * 16 + (lane >> 4) * 4 + r;
            int r9 = m % 9;
#pragma unroll
            for (int bj = 0; bj < 4; bj++) {
                int n = n0 + ch * 64 + bj * 16 + (lane & 15);
                float v = acc[bi][bj][r];
                if (bias1) v += bias1[n];
                if (prow) v += prow[r9 * ldp + n];
                if (outF) outF[(size_t)m * ldo + n] = v;
                if (outB) outB[(size_t)m * ldo + n] = f2b(v);
            }
        }
    }
}

// ---------------------------------------------------------------------------
// weight transpose+convert: out[n*ldo + k] = bf16(src[(off0+k)*N + n])
// ---------------------------------------------------------------------------
#define NJOBS 16
struct TJobsArg {
    const float* src[NJOBS];
    long dst[NJOBS];
    int K[NJOBS], N[NJOBS], off0[NJOBS], ldo[NJOBS];
};

__global__ __launch_bounds__(256) void tw_kernel(TJobsArg ja, ushort* wbuf)
{
    int j = blockIdx.y;
    int K = ja.K[j], N = ja.N[j];
    int tk = K >> 5, tn = N >> 5;
    int t = blockIdx.x;
    if (t >= tk * tn) return;
    int kt = t % tk, nt = t / tk;
    const float* src = ja.src[j];
    ushort* out = wbuf + ja.dst[j];
    int ldo = ja.ldo[j];
    __shared__ float L[32][33];
    int r = threadIdx.x >> 5, c = threadIdx.x & 31;
#pragma unroll
    for (int rr = 0; rr < 4; rr++) {
        int k = kt * 32 + rr * 8 + r;
        L[rr * 8 + r][c] = src[(size_t)(ja.off0[j] + k) * N + nt * 32 + c];
    }
    __syncthreads();
#pragma unroll
    for (int rr = 0; rr < 4; rr++) {
        int n = nt * 32 + rr * 8 + r;
        out[(size_t)n * ldo + kt * 32 + c] = f2b(L[c][rr * 8 + r]);
    }
}

// fp32 -> bf16 bulk convert (count % 4 == 0)
__global__ void f2b_kernel(const float* __restrict__ s, ushort* __restrict__ d, int n4)
{
    int i = blockIdx.x * blockDim.x + threadIdx.x;
    if (i >= n4) return;
    float4 v = ((const float4*)s)[i];
    ushort4 o;
    o.x = f2b(v.x); o.y = f2b(v.y); o.z = f2b(v.z); o.w = f2b(v.w);
    ((ushort4*)d)[i] = o;
}

// proj partial reduce: ixa1[n][0..256) = bf16(P0+P1+bias), low rows then high
__global__ void pjred_kernel(const float* __restrict__ PT,
                             const float* __restrict__ bl, const float* __restrict__ bh,
                             ushort* __restrict__ ixa1)
{
    int i = blockIdx.x * 256 + threadIdx.x;
    if (i >= NN2 * 64) return;
    int n = i >> 6, cq = i & 63;
    const float *p0, *p1, *bb; int r;
    if (n < NN) { p0 = PT; p1 = PT + (size_t)NN * 256; bb = bl; r = n; }
    else { p0 = PT + (size_t)2 * NN * 256; p1 = PT + (size_t)3 * NN * 256; bb = bh; r = n - NN; }
    float4 a = ((const float4*)(p0 + (size_t)r * 256))[cq];
    float4 b = ((const float4*)(p1 + (size_t)r * 256))[cq];
    float4 bs = ((const float4*)bb)[cq];
    ushort4 o;
    o.x = f2b(a.x + b.x + bs.x); o.y = f2b(a.y + b.y + bs.y);
    o.z = f2b(a.z + b.z + bs.z); o.w = f2b(a.w + b.w + bs.w);
    ((ushort4*)(ixa1 + (size_t)n * 512))[cq] = o;
}

// ---------------------------------------------------------------------------
// Graph-per-block edge kernel. PB row n: [Pd(O)|Ps(O)|Ad(O)|As(O)|skip(O)].
// ---------------------------------------------------------------------------
__global__ __launch_bounds__(256) void edge_kernel(
    const ushort* __restrict__ PB, const float* __restrict__ att2_w,
    ushort* __restrict__ Gout, int ldG, float* __restrict__ S, int O, int cshift)
{
    __shared__ ushort sPB[9 * 2048];
    __shared__ float sAw[512];
    __shared__ float logits[72];
    __shared__ float aw[72];
    const int g = blockIdx.x;
    const int tid = threadIdx.x, lane = tid & 63, wave = tid >> 6;
    const int O4 = O * 4, O5 = O * 5;
    const int cpr = O >> 7;
    const int total = 9 * cpr;
    const ushort* gbase = PB + (size_t)g * 9 * O5;

    for (int i = wave; i < total; i += 4) {
        int row = i / cpr, co = i - row * cpr;
        gload16(gbase + (size_t)row * O5 + co * 512 + lane * 8, sPB + i * 512);
    }
    for (int c = tid; c < O; c += 256) sAw[c] = att2_w[c];
    __syncthreads();

    for (int e = wave; e < 72; e += 4) {
        int d = e >> 3, k = e & 7;
        int s = k + (k >= d);
        const ushort* ad = sPB + d * O4 + 2 * O;
        const ushort* as = sPB + s * O4 + 3 * O;
        float p = 0.f;
        for (int c0 = lane * 4; c0 < O; c0 += 256) {
            ushort4 a4 = *(const ushort4*)(ad + c0);
            ushort4 s4 = *(const ushort4*)(as + c0);
            const ushort* ap = (const ushort*)&a4;
            const ushort* sp = (const ushort*)&s4;
#pragma unroll
            for (int j = 0; j < 4; j++) {
                float v = b2f(ap[j]) + b2f(sp[j]);
                v = v > 0.f ? v : 0.01f * v;
                p += v * sAw[c0 + j];
            }
        }
#pragma unroll
        for (int off = 32; off; off >>= 1) p += __shfl_down(p, off, 64);
        if (lane == 0) logits[e] = p;     // att2_b cancels in softmax
    }
    __syncthreads();

    if (tid < 9) {
        float m = -INFINITY;
#pragma unroll
        for (int k = 0; k < 8; k++) m = fmaxf(m, logits[tid * 8 + k]);
        float s = 0.f, ee[8];
#pragma unroll
        for (int k = 0; k < 8; k++) { ee[k] = expf(logits[tid * 8 + k] - m); s += ee[k]; }
        float inv = 1.0f / (s + 1e-16f);
#pragma unroll
        for (int k = 0; k < 8; k++) aw[tid * 8 + k] = ee[k] * inv;
        S[g * 9 + tid] = s * inv;
    }
    __syncthreads();

    const int nch = O >> 3;
    for (int idx = tid; idx < 9 * nch; idx += 256) {
        int n = idx >> cshift, cc = idx & (nch - 1);
        bf16x8 pdv = *(const bf16x8*)(sPB + n * O4 + cc * 8);
        const ushort* pp = (const ushort*)&pdv;
        float acc8[8];
#pragma unroll
        for (int j = 0; j < 8; j++) acc8[j] = 0.f;
#pragma unroll
        for (int k = 0; k < 8; k++) {
            int s = k + (k >= n);
            float w = aw[n * 8 + k];
            bf16x8 psv = *(const bf16x8*)(sPB + s * O4 + O + cc * 8);
            const ushort* qp = (const ushort*)&psv;
#pragma unroll
            for (int j = 0; j < 8; j++)
                acc8[j] += w * gelu_fast(b2f(pp[j]) + b2f(qp[j]));
        }
        ushort o8[8];
#pragma unroll
        for (int j = 0; j < 8; j++) o8[j] = f2b(acc8[j]);
        *(bf16x8*)(Gout + (size_t)(g * 9 + n) * ldG + cc * 8) = *(const bf16x8*)o8;
    }
}

// ---------------------------------------------------------------------------
// Fused upd-epilogue + LayerNorm:
//   t = P0+P1+ub[c]+vb[c]*S[n]+posU[(n%9)*O+c];  h = gelu(t) + skip(bf16)
//   LN(h) -> outB bf16 (row remap for rows >= rowsplit) or outF fp32
// ---------------------------------------------------------------------------
__global__ __launch_bounds__(256) void ln_kernel(
    const float* __restrict__ P0, const float* __restrict__ P1,
    const float* __restrict__ ub, const float* __restrict__ vb,
    const float* __restrict__ S, const float* __restrict__ posU,
    const ushort* __restrict__ PBs, int ld5,
    const float* __restrict__ gw, const float* __restrict__ bw,
    ushort* outB, int ldoB, int rowsplit, float* outF, int O)
{
    __shared__ float sm[4];
    const int n = blockIdx.x, tid = threadIdx.x;
    const int lane = tid & 63, wid = tid >> 6;
    const float* p0 = P0 + (size_t)n * O;
    const float* p1 = P1 + (size_t)n * O;
    const ushort* sr = PBs + (size_t)n * ld5;
    const float* pu = posU + (size_t)(n % 9) * O;
    const float sv = S[n];
    const int cnt = O >> 8;     // 1 or 2

    float vals[2];
    float sum = 0.f;
#pragma unroll
    for (int i = 0; i < 2; i++) {
        if (i < cnt) {
            int c = tid + 256 * i;
            float t = p0[c] + p1[c] + ub[c] + vb[c] * sv + pu[c];
            vals[i] = gelu_f(t) + b2f(sr[c]);
            sum += vals[i];
        }
    }
#pragma unroll
    for (int off = 32; off; off >>= 1) sum += __shfl_down(sum, off, 64);
    if (lane == 0) sm[wid] = sum;
    __syncthreads();
    const float mu = (sm[0] + sm[1] + sm[2] + sm[3]) / (float)O;
    __syncthreads();

    float var = 0.f;
#pragma unroll
    for (int i = 0; i < 2; i++) {
        if (i < cnt) { float d = vals[i] - mu; var += d * d; }
    }
#pragma unroll
    for (int off = 32; off; off >>= 1) var += __shfl_down(var, off, 64);
    if (lane == 0) sm[wid] = var;
    __syncthreads();
    const float rstd = rsqrtf((sm[0] + sm[1] + sm[2] + sm[3]) / (float)O + 1e-5f);

    int orow = n, coloff = 0;
    if (n >= rowsplit) { orow = n - rowsplit; coloff = 256; }
#pragma unroll
    for (int i = 0; i < 2; i++) {
        if (i < cnt) {
            int c = tid + 256 * i;
            float v = (vals[i] - mu) * rstd * gw[c] + bw[c];
            if (outB) outB[(size_t)orow * ldoB + coloff + c] = f2b(v);
            if (outF) outF[(size_t)n * O + c] = v;
        }
    }
}

// ---------------------------------------------------------------------------
// prep: concat biases, pos tables (posPB/posU), vb, pw2 bf16 copies
// ---------------------------------------------------------------------------
__global__ void prep_kernel(
    const float* __restrict__ pw1_b1, const float* __restrict__ att1_b1, const float* __restrict__ skip_b1,
    const float* __restrict__ pw1_b2, const float* __restrict__ att1_b2, const float* __restrict__ skip_b2,
    const float* __restrict__ pos_table,
    const float* __restrict__ s1_pw1, const float* __restrict__ s1_att, const float* __restrict__ s1_skp,
    const float* __restrict__ s2_pw1, const float* __restrict__ s2_att, const float* __restrict__ s2_skp,
    const float* __restrict__ pw2_b1, const float* __restrict__ upd_w1,
    const float* __restrict__ pw2_b2, const float* __restrict__ upd_w2,
    const float* __restrict__ pw2_w1, const float* __restrict__ pw2_w2,
    float* biasC1, float* biasC2,
    float* posPB1, float* posPB2, float* posU1, float* posU2,
    float* vb1, float* vb2, ushort* pw2f1, ushort* pw2f2)
{
    int i = blockIdx.x * 256 + threadIdx.x;
    if (i < 1280) {
        float v;
        if (i < 256) v = pw1_b1[i];
        else if (i < 512) v = 0.f;
        else if (i < 768) v = att1_b1[i - 512];
        else if (i < 1024) v = 0.f;
        else v = skip_b1[i - 1024];
        biasC1[i] = v;
        return;
    }
    i -= 1280;
    if (i < 2560) {
        float v;
        if (i < 512) v = pw1_b2[i];
        else if (i < 1024) v = 0.f;
        else if (i < 1536) v = att1_b2[i - 1024];
        else if (i < 2048) v = 0.f;
        else v = skip_b2[i - 2048];
        biasC2[i] = v;
        return;
    }
    i -= 2560;
    if (i < 9 * 1280) {   // posPB1[r][n]
        int r = i / 1280, n = i - r * 1280;
        int sec = n >> 8, c = n & 255;
        const float* src; int row0;
        if (sec == 0) { src = s1_pw1; row0 = 256; }
        else if (sec == 1) { src = s1_pw1; row0 = 576; }
        else if (sec == 2) { src = s1_att; row0 = 512; }
        else if (sec == 3) { src = s1_att; row0 = 576; }
        else { src = s1_skp; row0 = 256; }
        float a = 0.f;
        for (int k = 0; k < 64; k++) a += pos_table[r * 64 + k] * src[(size_t)(row0 + k) * 256 + c];
        posPB1[i] = a;
        return;
    }
    i -= 9 * 1280;
    if (i < 9 * 2560) {   // posPB2[r][n]
        int r = i / 2560, n = i - r * 2560;
        int sec = n >> 9, c = n & 511;
        const float* src; int row0;
        if (sec == 0) { src = s2_pw1; row0 = 512; }
        else if (sec == 1) { src = s2_pw1; row0 = 1088; }
        else if (sec == 2) { src = s2_att; row0 = 1024; }
        else if (sec == 3) { src = s2_att; row0 = 1088; }
        else { src = s2_skp; row0 = 512; }
        float a = 0.f;
        for (int k = 0; k < 64; k++) a += pos_table[r * 64 + k] * src[(size_t)(row0 + k) * 512 + c];
        posPB2[i] = a;
        return;
    }
    i -= 9 * 2560;
    if (i < 9 * 256) {    // posU1
        int r = i >> 8, c = i & 255;
        float a = 0.f;
        for (int k = 0; k < 64; k++) a += pos_table[r * 64 + k] * upd_w1[(size_t)(256 + k) * 256 + c];
        posU1[i] = a;
        return;
    }
    i -= 9 * 256;
    if (i < 9 * 512) {    // posU2
        int r = i >> 9, c = i & 511;
        float a = 0.f;
        for (int k = 0; k < 64; k++) a += pos_table[r * 64 + k] * upd_w2[(size_t)(512 + k) * 512 + c];
        posU2[i] = a;
        return;
    }
    i -= 9 * 512;
    if (i < 256) {        // vb1[n] = sum_j pw2_b1[j] * upd_w1[(320+j)][n]
        float a = 0.f;
        for (int j = 0; j < 256; j++) a += pw2_b1[j] * upd_w1[(size_t)(320 + j) * 256 + i];
        vb1[i] = a;
        return;
    }
    i -= 256;
    if (i < 512) {        // vb2
        float a = 0.f;
        for (int j = 0; j < 512; j++) a += pw2_b2[j] * upd_w2[(size_t)(576 + j) * 512 + i];
        vb2[i] = a;
        return;
    }
    i -= 512;
    if (i < 256 * 256) { pw2f1[i] = f2b(pw2_w1[i]); return; }
    i -= 256 * 256;
    if (i < 512 * 512) { pw2f2[i] = f2b(pw2_w2[i]); return; }
}

// ---------------------------------------------------------------------------
// head: pool(9 rows) + cls1 (gelu) + cls2, 4 graphs per block
// ---------------------------------------------------------------------------
__global__ __launch_bounds__(256) void head_kernel(
    const float* __restrict__ h2,
    const float* __restrict__ cls1_w, const float* __restrict__ cls1_b,
    const float* __restrict__ cls2_w, const float* __restrict__ cls2_b,
    float* __restrict__ out)
{
    __shared__ float pooled[4][512];
    __shared__ float hid[4][256];
    const int b = blockIdx.x, tid = threadIdx.x;

    for (int idx = tid; idx < 4 * 512; idx += 256) {
        int gi = idx >> 9, c = idx & 511;
        const float* base = h2 + (size_t)((b * 4 + gi) * 9) * 512 + c;
        float s = 0.f;
#pragma unroll
        for (int k = 0; k < NPG; k++) s += base[(size_t)k * 512];
        pooled[gi][c] = s;
    }
    __syncthreads();

    {
        float acc[4] = {0.f, 0.f, 0.f, 0.f};
        for (int c = 0; c < 512; c++) {
            float w = cls1_w[(size_t)c * 256 + tid];
#pragma unroll
            for (int gi = 0; gi < 4; gi++) acc[gi] += pooled[gi][c] * w;
        }
        float bb = cls1_b[tid];
#pragma unroll
        for (int gi = 0; gi < 4; gi++) hid[gi][tid] = gelu_f(acc[gi] + bb);
    }
    __syncthreads();

    {
        int gi = tid >> 6, lane = tid & 63;
        float p = 0.f;
#pragma unroll
        for (int i = 0; i < 4; i++) p += hid[gi][lane + 64 * i] * cls2_w[lane + 64 * i];
#pragma unroll
        for (int off = 32; off; off >>= 1) p += __shfl_down(p, off, 64);
        if (lane == 0) out[b * 4 + gi] = p + cls2_b[0];
    }
}

// ---------------------------------------------------------------------------
// Host side
// ---------------------------------------------------------------------------
static inline void mg(hipStream_t st, int M, int N, int K,
                      const ushort* A, int lda, const ushort* Wt, int ldw,
                      const float* bias1, const float* prow, int ldp,
                      float* outF, ushort* outB, int ldo,
                      int nz, long partStride)
{
    dim3 grid(N / 128, M / 128, nz);
    mgemm<<<grid, dim3(256), 0, st>>>(A, lda, Wt, ldw, bias1, prow, ldp,
                                      outF, outB, ldo, partStride, K);
}

extern "C" void kernel_launch(void* const* d_in, const int* in_sizes, int n_in,
                              void* d_out, int out_size, void* d_ws, size_t ws_size,
                              hipStream_t stream)
{
    (void)in_sizes; (void)n_in; (void)out_size; (void)ws_size;
    const float* feat_low   = (const float*)d_in[0];
    const float* feat_high  = (const float*)d_in[1];
    const float* pos_table  = (const float*)d_in[4];
    const float* proj_low_w  = (const float*)d_in[5];
    const float* proj_low_b  = (const float*)d_in[6];
    const float* proj_high_w = (const float*)d_in[7];
    const float* proj_high_b = (const float*)d_in[8];
    const float* cls1_w = (const float*)d_in[37];
    const float* cls1_b = (const float*)d_in[38];
    const float* cls2_w = (const float*)d_in[39];
    const float* cls2_b = (const float*)d_in[40];
    float* out = (float*)d_out;

    const float* s1_pw1 = (const float*)d_in[9];
    const float* s1_att = (const float*)d_in[13];
    const float* s1_upd = (const float*)d_in[17];
    const float* s1_skp = (const float*)d_in[21];
    const float* s2_pw1 = (const float*)d_in[23];
    const float* s2_att = (const float*)d_in[27];
    const float* s2_upd = (const float*)d_in[31];
    const float* s2_skp = (const float*)d_in[35];

    const float* att2_w1 = (const float*)d_in[15];
    const float* upd_b1  = (const float*)d_in[18];
    const float* ln_g1   = (const float*)d_in[19];
    const float* ln_b1   = (const float*)d_in[20];
    const float* att2_w2 = (const float*)d_in[29];
    const float* upd_b2  = (const float*)d_in[32];
    const float* ln_g2   = (const float*)d_in[33];
    const float* ln_b2   = (const float*)d_in[34];

    // ---- workspace layout (256B aligned) ----
    char* base = (char*)d_ws;
    size_t cur = 0;
    auto alloc = [&](size_t bytes) { void* p = base + cur; cur += (bytes + 255) & ~(size_t)255; return p; };
    void*   PBreg = alloc((size_t)NN * 2560 * 2);   // PB (s1: 18432x1280, s2: 9216x2560); featB alias
    ushort* PB    = (ushort*)PBreg;
    ushort* featB = (ushort*)PBreg;
    void*   IX1reg = alloc((size_t)NN2 * 512 * 2);  // ixa1 bf16; h2 fp32 alias (disjoint in time)
    ushort* ixa1  = (ushort*)IX1reg;
    float*  h2    = (float*)IX1reg;
    ushort* ixa2  = (ushort*)alloc((size_t)NN * 1024 * 2);
    float*  PT    = (float*)alloc((size_t)4 * NN * 256 * 4);  // split-K partials
    float*  S     = (float*)alloc((size_t)NN2 * 4);
    float*  biasC1 = (float*)alloc(1280 * 4);
    float*  biasC2 = (float*)alloc(2560 * 4);
    float*  posPB1 = (float*)alloc(9 * 1280 * 4);
    float*  posPB2 = (float*)alloc(9 * 2560 * 4);
    float*  posU1  = (float*)alloc(9 * 256 * 4);
    float*  posU2  = (float*)alloc(9 * 512 * 4);
    float*  vb1   = (float*)alloc(256 * 4);
    float*  vb2   = (float*)alloc(512 * 4);
    ushort* wbuf  = (ushort*)alloc((size_t)3400000 * 2);

    // ---- weight transpose jobs (x-parts only; pos handled via prow tables) ----
    TJobsArg ja;
    long woff[16];
    {
        struct J { const float* s; int K, N, off0, ldo; long sz; };
        J js[NJOBS] = {
            {proj_low_w,  512, 256, 0, 512, 512L * 256},     // 0 projL
            {proj_high_w, 1024, 256, 0, 1024, 1024L * 256},  // 1 projH
            {s1_pw1, 256, 256, 0, 256, 256L * 256},          // 2 big5-1: pw1d
            {s1_pw1, 256, 256, 320, 256, 256L * 256},        // 3 pw1s
            {s1_att, 256, 256, 0, 256, 256L * 256},          // 4 attd
            {s1_att, 256, 256, 256, 256, 256L * 256},        // 5 atts
            {s1_skp, 256, 256, 0, 256, 256L * 256},          // 6 skip
            {s1_upd, 256, 256, 0, 512, 512L * 256},          // 7 updW1 (x cols)
            {s1_upd, 256, 256, 320, 256, 256L * 256},        // 8 updbT1 (aggr rows)
            {s2_pw1, 512, 512, 0, 512, 512L * 512},          // 9 big5-2: pw1d
            {s2_pw1, 512, 512, 576, 512, 512L * 512},        // 10 pw1s
            {s2_att, 512, 512, 0, 512, 512L * 512},          // 11 attd
            {s2_att, 512, 512, 512, 512, 512L * 512},        // 12 atts
            {s2_skp, 512, 512, 0, 512, 512L * 512},          // 13 skip
            {s2_upd, 512, 512, 0, 1024, 1024L * 512},        // 14 updW2 (x cols)
            {s2_upd, 512, 512, 576, 512, 512L * 512},        // 15 updbT2
        };
        long off = 0;
        for (int i = 0; i < NJOBS; i++) {
            ja.src[i] = js[i].s; ja.K[i] = js[i].K; ja.N[i] = js[i].N;
            ja.off0[i] = js[i].off0; ja.ldo[i] = js[i].ldo;
            ja.dst[i] = off; woff[i] = off;
            off += js[i].sz;
        }
    }
    long pw2off1 = woff[15] + 512L * 512;
    long pw2off2 = pw2off1 + 256L * 256;
    tw_kernel<<<dim3(256, NJOBS), dim3(256), 0, stream>>>(ja, wbuf);

    ushort* wBig5_1 = wbuf + woff[2];
    ushort* updW1   = wbuf + woff[7];
    ushort* updbT1  = wbuf + woff[8];
    ushort* wBig5_2 = wbuf + woff[9];
    ushort* updW2   = wbuf + woff[14];
    ushort* updbT2  = wbuf + woff[15];
    ushort* pw2f1   = wbuf + pw2off1;
    ushort* pw2f2   = wbuf + pw2off2;

    // ---- prep ----
    {
        int tot = 1280 + 2560 + 9 * 1280 + 9 * 2560 + 9 * 256 + 9 * 512
                + 256 + 512 + 256 * 256 + 512 * 512;
        prep_kernel<<<dim3((tot + 255) / 256), dim3(256), 0, stream>>>(
            (const float*)d_in[10], (const float*)d_in[14], (const float*)d_in[22],
            (const float*)d_in[24], (const float*)d_in[28], (const float*)d_in[36],
            pos_table,
            s1_pw1, s1_att, s1_skp, s2_pw1, s2_att, s2_skp,
            (const float*)d_in[12], s1_upd, (const float*)d_in[26], s2_upd,
            (const float*)d_in[11], (const float*)d_in[25],
            biasC1, biasC2, posPB1, posPB2, posU1, posU2, vb1, vb2, pw2f1, pw2f2);
    }

    // ---- Wcomb = pw2 @ updb, transposed into updW G-columns ----
    mg(stream, 256, 256, 256, updbT1, 256, pw2f1, 256, 0, 0, 0, 0, updW1 + 256, 512, 1, 0);
    mg(stream, 512, 512, 512, updbT2, 512, pw2f2, 512, 0, 0, 0, 0, updW2 + 512, 1024, 1, 0);

    // ---- projections (split-K z=2, partials in PT, reduce to ixa1) ----
    f2b_kernel<<<dim3(NN * 512 / 4 / 256), dim3(256), 0, stream>>>(feat_low, featB, NN * 512 / 4);
    f2b_kernel<<<dim3(NN * 1024 / 4 / 256), dim3(256), 0, stream>>>(
        feat_high, featB + (size_t)NN * 512, NN * 1024 / 4);
    mg(stream, NN, 256, 256, featB, 512, wbuf + woff[0], 512, 0, 0, 0,
       PT, 0, 256, 2, (long)NN * 256);
    mg(stream, NN, 256, 512, featB + (size_t)NN * 512, 1024, wbuf + woff[1], 1024, 0, 0, 0,
       PT + (size_t)2 * NN * 256, 0, 256, 2, (long)NN * 256);
    pjred_kernel<<<dim3(NN2 * 64 / 256), dim3(256), 0, stream>>>(PT, proj_low_b, proj_high_b, ixa1);

    // ---- stage 1 (batched, M = 18432) ----
    mg(stream, NN2, 1280, 256, ixa1, 512, wBig5_1, 256, biasC1, posPB1, 1280, 0, PB, 1280, 1, 0);
    edge_kernel<<<dim3(2 * NUM_GRAPHS), dim3(256), 0, stream>>>(
        PB, att2_w1, ixa1 + 256, 512, S, 256, 5);
    mg(stream, NN2, 256, 256, ixa1, 512, updW1, 512, 0, 0, 0, PT, 0, 256, 2, (long)NN2 * 256);
    ln_kernel<<<dim3(NN2), dim3(256), 0, stream>>>(
        PT, PT + (size_t)NN2 * 256, upd_b1, vb1, S, posU1,
        PB + 4 * 256, 1280, ln_g1, ln_b1, ixa2, 1024, NN, 0, 256);

    // ---- stage 2 ----
    mg(stream, NN, 2560, 512, ixa2, 1024, wBig5_2, 512, biasC2, posPB2, 2560, 0, PB, 2560, 1, 0);
    edge_kernel<<<dim3(NUM_GRAPHS), dim3(256), 0, stream>>>(
        PB, att2_w2, ixa2 + 512, 1024, S, 512, 6);
    mg(stream, NN, 512, 512, ixa2, 1024, updW2, 1024, 0, 0, 0, PT, 0, 512, 2, (long)NN * 512);
    ln_kernel<<<dim3(NN), dim3(256), 0, stream>>>(
        PT, PT + (size_t)NN * 512, upd_b2, vb2, S, posU2,
        PB + 4 * 512, 2560, ln_g2, ln_b2, 0, 0, 1 << 30, h2, 512);

    // ---- head ----
    head_kernel<<<dim3(NUM_GRAPHS / 4), dim3(256), 0, stream>>>(h2, cls1_w, cls1_b, cls2_w, cls2_b, out);
}

// Round 10
// 581.379 us; speedup vs baseline: 1.0509x; 1.0509x over previous
//
#include <hip/hip_runtime.h>
#include <math.h>

// ---------- model constants ----------
#define NUM_GRAPHS 1024
#define NPG 9
#define NN 9216            // nodes
#define NN2 18432          // batched stage-1 rows (low|high)
#define POSD 64

typedef __attribute__((ext_vector_type(8))) short bf16x8;
typedef __attribute__((ext_vector_type(4))) float f32x4;

__device__ __forceinline__ float gelu_f(float x) {
    return 0.5f * x * (1.0f + erff(x * 0.70710678118654752f));
}
// fast gelu (tanh form), |err| <= ~3e-3 vs erf-gelu (edge aggregation only)
__device__ __forceinline__ float gelu_fast(float x) {
    float y = 0.7978845608f * x * (1.0f + 0.044715f * x * x);
    float t = __expf(-2.0f * fabsf(y));
    float r = (1.0f - t) / (1.0f + t);
    r = copysignf(r, y);
    return 0.5f * x * (1.0f + r);
}
__device__ __forceinline__ ushort f2b(float v) {
    unsigned u = __float_as_uint(v);
    return (ushort)((u + 0x7fffu + ((u >> 16) & 1u)) >> 16);
}
__device__ __forceinline__ float b2f(ushort u) {
    return __uint_as_float(((unsigned)u) << 16);
}
__device__ __forceinline__ void gload16(const ushort* g, ushort* l) {
    __builtin_amdgcn_global_load_lds((const __attribute__((address_space(1))) void*)g,
                                     (__attribute__((address_space(3))) void*)l, 16, 0, 0);
}

// ---------------------------------------------------------------------------
// bf16 MFMA GEMM, double-buffered, optional split-K via blockIdx.z.
// C[M,N] = A[M,K@z]bf16 @ Wt[N,K@z]^T + bias1[n] + prow[(m%9)*ldp + n]
// Tile 128x128, 4 waves, BK=32. outF gets per-chunk partials (+z*partStride).
// (R7 proven version — R8 3-stage and R9 no-barrier variants were neutral/broken.)
// ---------------------------------------------------------------------------
__global__ __launch_bounds__(256, 4) void mgemm(
    const ushort* __restrict__ A, int lda,
    const ushort* __restrict__ Wt, int ldw,
    const float* __restrict__ bias1,
    const float* __restrict__ prow, int ldp,
    float* outF, ushort* outB, int ldo,
    long partStride, int K)
{
    __shared__ ushort sA[2][128 * 32];
    __shared__ ushort sB[2][128 * 32];
    const int wv = threadIdx.x >> 6, lane = threadIdx.x & 63;
    const int rh = wv & 1, ch = wv >> 1;
    const int m0 = blockIdx.y * 128, n0 = blockIdx.x * 128;
    const int koff = blockIdx.z * K;

    f32x4 acc[4][4];
#pragma unroll
    for (int i = 0; i < 4; i++)
#pragma unroll
        for (int j = 0; j < 4; j++) acc[i][j] = (f32x4){0.f, 0.f, 0.f, 0.f};

    const ushort* Ab = A + (size_t)m0 * lda + koff;
    const ushort* Wb = Wt + (size_t)n0 * ldw + koff;
    if (outF) outF += (size_t)blockIdx.z * partStride;

    auto stage = [&](int b, int k0) {
#pragma unroll
        for (int i = 0; i < 2; i++) {
            int c = wv * 2 + i;
            int u = c * 64 + lane;
            int row = u >> 2, p = u & 3;
            int q = (p - (row >> 1)) & 3;
            gload16(Ab + (size_t)row * lda + k0 + q * 8, sA[b] + c * 512);
            gload16(Wb + (size_t)row * ldw + k0 + q * 8, sB[b] + c * 512);
        }
    };

    const int nsteps = K >> 5;
    stage(0, 0);
    int buf = 0;
    for (int s = 0; s < nsteps; s++) {
        __syncthreads();                       // prefetch for buf complete
        if (s + 1 < nsteps) stage(buf ^ 1, (s + 1) << 5);
        const int qg = lane >> 4;
        bf16x8 af[4], bfr[4];
#pragma unroll
        for (int bi = 0; bi < 4; bi++) {
            int r = rh * 64 + bi * 16 + (lane & 15);
            af[bi] = *(const bf16x8*)(sA[buf] + (r * 4 + ((qg + (r >> 1)) & 3)) * 8);
        }
#pragma unroll
        for (int bj = 0; bj < 4; bj++) {
            int r = ch * 64 + bj * 16 + (lane & 15);
            bfr[bj] = *(const bf16x8*)(sB[buf] + (r * 4 + ((qg + (r >> 1)) & 3)) * 8);
        }
#pragma unroll
        for (int bi = 0; bi < 4; bi++)
#pragma unroll
            for (int bj = 0; bj < 4; bj++)
                acc[bi][bj] = __builtin_amdgcn_mfma_f32_16x16x32_bf16(
                    af[bi], bfr[bj], acc[bi][bj], 0, 0, 0);
        buf ^= 1;
    }

#pragma unroll
    for (int bi = 0; bi < 4; bi++) {
#pragma unroll
        for (int r = 0; r < 4; r++) {
            int m = m0 + rh * 64 + bi * 16 + (lane >> 4) * 4 + r;
            int r9 = m % 9;
#pragma unroll
            for (int bj = 0; bj < 4; bj++) {
                int n = n0 + ch * 64 + bj * 16 + (lane & 15);
                float v = acc[bi][bj][r];
                if (bias1) v += bias1[n];
                if (prow) v += prow[r9 * ldp + n];
                if (outF) outF[(size_t)m * ldo + n] = v;
                if (outB) outB[(size_t)m * ldo + n] = f2b(v);
            }
        }
    }
}

// ---------------------------------------------------------------------------
// weight transpose+convert: out[n*ldo + k] = bf16(src[(off0+k)*N + n])
// ---------------------------------------------------------------------------
#define NJOBS 16
struct TJobsArg {
    const float* src[NJOBS];
    long dst[NJOBS];
    int K[NJOBS], N[NJOBS], off0[NJOBS], ldo[NJOBS];
};

__global__ __launch_bounds__(256) void tw_kernel(TJobsArg ja, ushort* wbuf)
{
    int j = blockIdx.y;
    int K = ja.K[j], N = ja.N[j];
    int tk = K >> 5, tn = N >> 5;
    int t = blockIdx.x;
    if (t >= tk * tn) return;
    int kt = t % tk, nt = t / tk;
    const float* src = ja.src[j];
    ushort* out = wbuf + ja.dst[j];
    int ldo = ja.ldo[j];
    __shared__ float L[32][33];
    int r = threadIdx.x >> 5, c = threadIdx.x & 31;
#pragma unroll
    for (int rr = 0; rr < 4; rr++) {
        int k = kt * 32 + rr * 8 + r;
        L[rr * 8 + r][c] = src[(size_t)(ja.off0[j] + k) * N + nt * 32 + c];
    }
    __syncthreads();
#pragma unroll
    for (int rr = 0; rr < 4; rr++) {
        int n = nt * 32 + rr * 8 + r;
        out[(size_t)n * ldo + kt * 32 + c] = f2b(L[c][rr * 8 + r]);
    }
}

// proj partial reduce: ixa1[n][0..256) = bf16(P0+P1+bias), low rows then high
__global__ void pjred_kernel(const float* __restrict__ PT,
                             const float* __restrict__ bl, const float* __restrict__ bh,
                             ushort* __restrict__ ixa1)
{
    int i = blockIdx.x * 256 + threadIdx.x;
    if (i >= NN2 * 64) return;
    int n = i >> 6, cq = i & 63;
    const float *p0, *p1, *bb; int r;
    if (n < NN) { p0 = PT; p1 = PT + (size_t)NN * 256; bb = bl; r = n; }
    else { p0 = PT + (size_t)2 * NN * 256; p1 = PT + (size_t)3 * NN * 256; bb = bh; r = n - NN; }
    float4 a = ((const float4*)(p0 + (size_t)r * 256))[cq];
    float4 b = ((const float4*)(p1 + (size_t)r * 256))[cq];
    float4 bs = ((const float4*)bb)[cq];
    ushort4 o;
    o.x = f2b(a.x + b.x + bs.x); o.y = f2b(a.y + b.y + bs.y);
    o.z = f2b(a.z + b.z + bs.z); o.w = f2b(a.w + b.w + bs.w);
    ((ushort4*)(ixa1 + (size_t)n * 512))[cq] = o;
}

// ---------------------------------------------------------------------------
// Graph-per-block edge kernel. PB row n: [Pd(O)|Ps(O)|Ad(O)|As(O)|skip(O)].
// ---------------------------------------------------------------------------
__global__ __launch_bounds__(256) void edge_kernel(
    const ushort* __restrict__ PB, const float* __restrict__ att2_w,
    ushort* __restrict__ Gout, int ldG, float* __restrict__ S, int O, int cshift)
{
    __shared__ ushort sPB[9 * 2048];
    __shared__ float sAw[512];
    __shared__ float logits[72];
    __shared__ float aw[72];
    const int g = blockIdx.x;
    const int tid = threadIdx.x, lane = tid & 63, wave = tid >> 6;
    const int O4 = O * 4, O5 = O * 5;
    const int cpr = O >> 7;
    const int total = 9 * cpr;
    const ushort* gbase = PB + (size_t)g * 9 * O5;

    for (int i = wave; i < total; i += 4) {
        int row = i / cpr, co = i - row * cpr;
        gload16(gbase + (size_t)row * O5 + co * 512 + lane * 8, sPB + i * 512);
    }
    for (int c = tid; c < O; c += 256) sAw[c] = att2_w[c];
    __syncthreads();

    for (int e = wave; e < 72; e += 4) {
        int d = e >> 3, k = e & 7;
        int s = k + (k >= d);
        const ushort* ad = sPB + d * O4 + 2 * O;
        const ushort* as = sPB + s * O4 + 3 * O;
        float p = 0.f;
        for (int c0 = lane * 4; c0 < O; c0 += 256) {
            ushort4 a4 = *(const ushort4*)(ad + c0);
            ushort4 s4 = *(const ushort4*)(as + c0);
            const ushort* ap = (const ushort*)&a4;
            const ushort* sp = (const ushort*)&s4;
#pragma unroll
            for (int j = 0; j < 4; j++) {
                float v = b2f(ap[j]) + b2f(sp[j]);
                v = v > 0.f ? v : 0.01f * v;
                p += v * sAw[c0 + j];
            }
        }
#pragma unroll
        for (int off = 32; off; off >>= 1) p += __shfl_down(p, off, 64);
        if (lane == 0) logits[e] = p;     // att2_b cancels in softmax
    }
    __syncthreads();

    if (tid < 9) {
        float m = -INFINITY;
#pragma unroll
        for (int k = 0; k < 8; k++) m = fmaxf(m, logits[tid * 8 + k]);
        float s = 0.f, ee[8];
#pragma unroll
        for (int k = 0; k < 8; k++) { ee[k] = expf(logits[tid * 8 + k] - m); s += ee[k]; }
        float inv = 1.0f / (s + 1e-16f);
#pragma unroll
        for (int k = 0; k < 8; k++) aw[tid * 8 + k] = ee[k] * inv;
        S[g * 9 + tid] = s * inv;
    }
    __syncthreads();

    const int nch = O >> 3;
    for (int idx = tid; idx < 9 * nch; idx += 256) {
        int n = idx >> cshift, cc = idx & (nch - 1);
        bf16x8 pdv = *(const bf16x8*)(sPB + n * O4 + cc * 8);
        const ushort* pp = (const ushort*)&pdv;
        float acc8[8];
#pragma unroll
        for (int j = 0; j < 8; j++) acc8[j] = 0.f;
#pragma unroll
        for (int k = 0; k < 8; k++) {
            int s = k + (k >= n);
            float w = aw[n * 8 + k];
            bf16x8 psv = *(const bf16x8*)(sPB + s * O4 + O + cc * 8);
            const ushort* qp = (const ushort*)&psv;
#pragma unroll
            for (int j = 0; j < 8; j++)
                acc8[j] += w * gelu_fast(b2f(pp[j]) + b2f(qp[j]));
        }
        ushort o8[8];
#pragma unroll
        for (int j = 0; j < 8; j++) o8[j] = f2b(acc8[j]);
        *(bf16x8*)(Gout + (size_t)(g * 9 + n) * ldG + cc * 8) = *(const bf16x8*)o8;
    }
}

// ---------------------------------------------------------------------------
// Fused upd-epilogue + LayerNorm:
//   t = P0+P1+ub[c]+vb[c]*S[n]+posU[(n%9)*O+c];  h = gelu(t) + skip(bf16)
//   LN(h) -> outB bf16 (row remap for rows >= rowsplit) or outF fp32
// ---------------------------------------------------------------------------
__global__ __launch_bounds__(256) void ln_kernel(
    const float* __restrict__ P0, const float* __restrict__ P1,
    const float* __restrict__ ub, const float* __restrict__ vb,
    const float* __restrict__ S, const float* __restrict__ posU,
    const ushort* __restrict__ PBs, int ld5,
    const float* __restrict__ gw, const float* __restrict__ bw,
    ushort* outB, int ldoB, int rowsplit, float* outF, int O)
{
    __shared__ float sm[4];
    const int n = blockIdx.x, tid = threadIdx.x;
    const int lane = tid & 63, wid = tid >> 6;
    const float* p0 = P0 + (size_t)n * O;
    const float* p1 = P1 + (size_t)n * O;
    const ushort* sr = PBs + (size_t)n * ld5;
    const float* pu = posU + (size_t)(n % 9) * O;
    const float sv = S[n];
    const int cnt = O >> 8;     // 1 or 2

    float vals[2];
    float sum = 0.f;
#pragma unroll
    for (int i = 0; i < 2; i++) {
        if (i < cnt) {
            int c = tid + 256 * i;
            float t = p0[c] + p1[c] + ub[c] + vb[c] * sv + pu[c];
            vals[i] = gelu_f(t) + b2f(sr[c]);
            sum += vals[i];
        }
    }
#pragma unroll
    for (int off = 32; off; off >>= 1) sum += __shfl_down(sum, off, 64);
    if (lane == 0) sm[wid] = sum;
    __syncthreads();
    const float mu = (sm[0] + sm[1] + sm[2] + sm[3]) / (float)O;
    __syncthreads();

    float var = 0.f;
#pragma unroll
    for (int i = 0; i < 2; i++) {
        if (i < cnt) { float d = vals[i] - mu; var += d * d; }
    }
#pragma unroll
    for (int off = 32; off; off >>= 1) var += __shfl_down(var, off, 64);
    if (lane == 0) sm[wid] = var;
    __syncthreads();
    const float rstd = rsqrtf((sm[0] + sm[1] + sm[2] + sm[3]) / (float)O + 1e-5f);

    int orow = n, coloff = 0;
    if (n >= rowsplit) { orow = n - rowsplit; coloff = 256; }
#pragma unroll
    for (int i = 0; i < 2; i++) {
        if (i < cnt) {
            int c = tid + 256 * i;
            float v = (vals[i] - mu) * rstd * gw[c] + bw[c];
            if (outB) outB[(size_t)orow * ldoB + coloff + c] = f2b(v);
            if (outF) outF[(size_t)n * O + c] = v;
        }
    }
}

// ---------------------------------------------------------------------------
// prep: concat biases, pos tables (posPB/posU), vb, pw2 bf16 copies,
//       and feat_low/feat_high fp32->bf16 conversion (merged f2b)
// ---------------------------------------------------------------------------
__global__ void prep_kernel(
    const float* __restrict__ pw1_b1, const float* __restrict__ att1_b1, const float* __restrict__ skip_b1,
    const float* __restrict__ pw1_b2, const float* __restrict__ att1_b2, const float* __restrict__ skip_b2,
    const float* __restrict__ pos_table,
    const float* __restrict__ s1_pw1, const float* __restrict__ s1_att, const float* __restrict__ s1_skp,
    const float* __restrict__ s2_pw1, const float* __restrict__ s2_att, const float* __restrict__ s2_skp,
    const float* __restrict__ pw2_b1, const float* __restrict__ upd_w1,
    const float* __restrict__ pw2_b2, const float* __restrict__ upd_w2,
    const float* __restrict__ pw2_w1, const float* __restrict__ pw2_w2,
    const float* __restrict__ feat_low, const float* __restrict__ feat_high,
    float* biasC1, float* biasC2,
    float* posPB1, float* posPB2, float* posU1, float* posU2,
    float* vb1, float* vb2, ushort* pw2f1, ushort* pw2f2, ushort* featB)
{
    int i = blockIdx.x * 256 + threadIdx.x;
    if (i < 1280) {
        float v;
        if (i < 256) v = pw1_b1[i];
        else if (i < 512) v = 0.f;
        else if (i < 768) v = att1_b1[i - 512];
        else if (i < 1024) v = 0.f;
        else v = skip_b1[i - 1024];
        biasC1[i] = v;
        return;
    }
    i -= 1280;
    if (i < 2560) {
        float v;
        if (i < 512) v = pw1_b2[i];
        else if (i < 1024) v = 0.f;
        else if (i < 1536) v = att1_b2[i - 1024];
        else if (i < 2048) v = 0.f;
        else v = skip_b2[i - 2048];
        biasC2[i] = v;
        return;
    }
    i -= 2560;
    if (i < 9 * 1280) {   // posPB1[r][n]
        int r = i / 1280, n = i - r * 1280;
        int sec = n >> 8, c = n & 255;
        const float* src; int row0;
        if (sec == 0) { src = s1_pw1; row0 = 256; }
        else if (sec == 1) { src = s1_pw1; row0 = 576; }
        else if (sec == 2) { src = s1_att; row0 = 512; }
        else if (sec == 3) { src = s1_att; row0 = 576; }
        else { src = s1_skp; row0 = 256; }
        float a = 0.f;
        for (int k = 0; k < 64; k++) a += pos_table[r * 64 + k] * src[(size_t)(row0 + k) * 256 + c];
        posPB1[i] = a;
        return;
    }
    i -= 9 * 1280;
    if (i < 9 * 2560) {   // posPB2[r][n]
        int r = i / 2560, n = i - r * 2560;
        int sec = n >> 9, c = n & 511;
        const float* src; int row0;
        if (sec == 0) { src = s2_pw1; row0 = 512; }
        else if (sec == 1) { src = s2_pw1; row0 = 1088; }
        else if (sec == 2) { src = s2_att; row0 = 1024; }
        else if (sec == 3) { src = s2_att; row0 = 1088; }
        else { src = s2_skp; row0 = 512; }
        float a = 0.f;
        for (int k = 0; k < 64; k++) a += pos_table[r * 64 + k] * src[(size_t)(row0 + k) * 512 + c];
        posPB2[i] = a;
        return;
    }
    i -= 9 * 2560;
    if (i < 9 * 256) {    // posU1
        int r = i >> 8, c = i & 255;
        float a = 0.f;
        for (int k = 0; k < 64; k++) a += pos_table[r * 64 + k] * upd_w1[(size_t)(256 + k) * 256 + c];
        posU1[i] = a;
        return;
    }
    i -= 9 * 256;
    if (i < 9 * 512) {    // posU2
        int r = i >> 9, c = i & 511;
        float a = 0.f;
        for (int k = 0; k < 64; k++) a += pos_table[r * 64 + k] * upd_w2[(size_t)(512 + k) * 512 + c];
        posU2[i] = a;
        return;
    }
    i -= 9 * 512;
    if (i < 256) {        // vb1[n] = sum_j pw2_b1[j] * upd_w1[(320+j)][n]
        float a = 0.f;
        for (int j = 0; j < 256; j++) a += pw2_b1[j] * upd_w1[(size_t)(320 + j) * 256 + i];
        vb1[i] = a;
        return;
    }
    i -= 256;
    if (i < 512) {        // vb2
        float a = 0.f;
        for (int j = 0; j < 512; j++) a += pw2_b2[j] * upd_w2[(size_t)(576 + j) * 512 + i];
        vb2[i] = a;
        return;
    }
    i -= 512;
    if (i < 256 * 256) { pw2f1[i] = f2b(pw2_w1[i]); return; }
    i -= 256 * 256;
    if (i < 512 * 512) { pw2f2[i] = f2b(pw2_w2[i]); return; }
    i -= 512 * 512;
    if (i < NN * 512 / 4) {   // feat_low -> featB bf16
        float4 v = ((const float4*)feat_low)[i];
        ushort4 o;
        o.x = f2b(v.x); o.y = f2b(v.y); o.z = f2b(v.z); o.w = f2b(v.w);
        ((ushort4*)featB)[i] = o;
        return;
    }
    i -= NN * 512 / 4;
    if (i < NN * 1024 / 4) {  // feat_high -> featB + NN*512
        float4 v = ((const float4*)feat_high)[i];
        ushort4 o;
        o.x = f2b(v.x); o.y = f2b(v.y); o.z = f2b(v.z); o.w = f2b(v.w);
        ((ushort4*)(featB + (size_t)NN * 512))[i] = o;
    }
}

// ---------------------------------------------------------------------------
// head: pool(9 rows) + cls1 (gelu) + cls2, 4 graphs per block
// ---------------------------------------------------------------------------
__global__ __launch_bounds__(256) void head_kernel(
    const float* __restrict__ h2,
    const float* __restrict__ cls1_w, const float* __restrict__ cls1_b,
    const float* __restrict__ cls2_w, const float* __restrict__ cls2_b,
    float* __restrict__ out)
{
    __shared__ float pooled[4][512];
    __shared__ float hid[4][256];
    const int b = blockIdx.x, tid = threadIdx.x;

    for (int idx = tid; idx < 4 * 512; idx += 256) {
        int gi = idx >> 9, c = idx & 511;
        const float* base = h2 + (size_t)((b * 4 + gi) * 9) * 512 + c;
        float s = 0.f;
#pragma unroll
        for (int k = 0; k < NPG; k++) s += base[(size_t)k * 512];
        pooled[gi][c] = s;
    }
    __syncthreads();

    {
        float acc[4] = {0.f, 0.f, 0.f, 0.f};
        for (int c = 0; c < 512; c++) {
            float w = cls1_w[(size_t)c * 256 + tid];
#pragma unroll
            for (int gi = 0; gi < 4; gi++) acc[gi] += pooled[gi][c] * w;
        }
        float bb = cls1_b[tid];
#pragma unroll
        for (int gi = 0; gi < 4; gi++) hid[gi][tid] = gelu_f(acc[gi] + bb);
    }
    __syncthreads();

    {
        int gi = tid >> 6, lane = tid & 63;
        float p = 0.f;
#pragma unroll
        for (int i = 0; i < 4; i++) p += hid[gi][lane + 64 * i] * cls2_w[lane + 64 * i];
#pragma unroll
        for (int off = 32; off; off >>= 1) p += __shfl_down(p, off, 64);
        if (lane == 0) out[b * 4 + gi] = p + cls2_b[0];
    }
}

// ---------------------------------------------------------------------------
// Host side
// ---------------------------------------------------------------------------
static inline void mg(hipStream_t st, int M, int N, int K,
                      const ushort* A, int lda, const ushort* Wt, int ldw,
                      const float* bias1, const float* prow, int ldp,
                      float* outF, ushort* outB, int ldo,
                      int nz, long partStride)
{
    dim3 grid(N / 128, M / 128, nz);
    mgemm<<<grid, dim3(256), 0, st>>>(A, lda, Wt, ldw, bias1, prow, ldp,
                                      outF, outB, ldo, partStride, K);
}

extern "C" void kernel_launch(void* const* d_in, const int* in_sizes, int n_in,
                              void* d_out, int out_size, void* d_ws, size_t ws_size,
                              hipStream_t stream)
{
    (void)in_sizes; (void)n_in; (void)out_size; (void)ws_size;
    const float* feat_low   = (const float*)d_in[0];
    const float* feat_high  = (const float*)d_in[1];
    const float* pos_table  = (const float*)d_in[4];
    const float* proj_low_w  = (const float*)d_in[5];
    const float* proj_low_b  = (const float*)d_in[6];
    const float* proj_high_w = (const float*)d_in[7];
    const float* proj_high_b = (const float*)d_in[8];
    const float* cls1_w = (const float*)d_in[37];
    const float* cls1_b = (const float*)d_in[38];
    const float* cls2_w = (const float*)d_in[39];
    const float* cls2_b = (const float*)d_in[40];
    float* out = (float*)d_out;

    const float* s1_pw1 = (const float*)d_in[9];
    const float* s1_att = (const float*)d_in[13];
    const float* s1_upd = (const float*)d_in[17];
    const float* s1_skp = (const float*)d_in[21];
    const float* s2_pw1 = (const float*)d_in[23];
    const float* s2_att = (const float*)d_in[27];
    const float* s2_upd = (const float*)d_in[31];
    const float* s2_skp = (const float*)d_in[35];

    const float* att2_w1 = (const float*)d_in[15];
    const float* upd_b1  = (const float*)d_in[18];
    const float* ln_g1   = (const float*)d_in[19];
    const float* ln_b1   = (const float*)d_in[20];
    const float* att2_w2 = (const float*)d_in[29];
    const float* upd_b2  = (const float*)d_in[32];
    const float* ln_g2   = (const float*)d_in[33];
    const float* ln_b2   = (const float*)d_in[34];

    // ---- workspace layout (256B aligned) ----
    char* base = (char*)d_ws;
    size_t cur = 0;
    auto alloc = [&](size_t bytes) { void* p = base + cur; cur += (bytes + 255) & ~(size_t)255; return p; };
    void*   PBreg = alloc((size_t)NN * 2560 * 2);   // PB (s1: 18432x1280, s2: 9216x2560); featB alias
    ushort* PB    = (ushort*)PBreg;
    ushort* featB = (ushort*)PBreg;
    void*   IX1reg = alloc((size_t)NN2 * 512 * 2);  // ixa1 bf16; h2 fp32 alias (disjoint in time)
    ushort* ixa1  = (ushort*)IX1reg;
    float*  h2    = (float*)IX1reg;
    ushort* ixa2  = (ushort*)alloc((size_t)NN * 1024 * 2);
    float*  PT    = (float*)alloc((size_t)4 * NN * 256 * 4);  // split-K partials
    float*  S     = (float*)alloc((size_t)NN2 * 4);
    float*  biasC1 = (float*)alloc(1280 * 4);
    float*  biasC2 = (float*)alloc(2560 * 4);
    float*  posPB1 = (float*)alloc(9 * 1280 * 4);
    float*  posPB2 = (float*)alloc(9 * 2560 * 4);
    float*  posU1  = (float*)alloc(9 * 256 * 4);
    float*  posU2  = (float*)alloc(9 * 512 * 4);
    float*  vb1   = (float*)alloc(256 * 4);
    float*  vb2   = (float*)alloc(512 * 4);
    ushort* wbuf  = (ushort*)alloc((size_t)3400000 * 2);

    // ---- weight transpose jobs (x-parts only; pos handled via prow tables) ----
    TJobsArg ja;
    long woff[16];
    {
        struct J { const float* s; int K, N, off0, ldo; long sz; };
        J js[NJOBS] = {
            {proj_low_w,  512, 256, 0, 512, 512L * 256},     // 0 projL
            {proj_high_w, 1024, 256, 0, 1024, 1024L * 256},  // 1 projH
            {s1_pw1, 256, 256, 0, 256, 256L * 256},          // 2 big5-1: pw1d
            {s1_pw1, 256, 256, 320, 256, 256L * 256},        // 3 pw1s
            {s1_att, 256, 256, 0, 256, 256L * 256},          // 4 attd
            {s1_att, 256, 256, 256, 256, 256L * 256},        // 5 atts
            {s1_skp, 256, 256, 0, 256, 256L * 256},          // 6 skip
            {s1_upd, 256, 256, 0, 512, 512L * 256},          // 7 updW1 (x cols)
            {s1_upd, 256, 256, 320, 256, 256L * 256},        // 8 updbT1 (aggr rows)
            {s2_pw1, 512, 512, 0, 512, 512L * 512},          // 9 big5-2: pw1d
            {s2_pw1, 512, 512, 576, 512, 512L * 512},        // 10 pw1s
            {s2_att, 512, 512, 0, 512, 512L * 512},          // 11 attd
            {s2_att, 512, 512, 512, 512, 512L * 512},        // 12 atts
            {s2_skp, 512, 512, 0, 512, 512L * 512},          // 13 skip
            {s2_upd, 512, 512, 0, 1024, 1024L * 512},        // 14 updW2 (x cols)
            {s2_upd, 512, 512, 576, 512, 512L * 512},        // 15 updbT2
        };
        long off = 0;
        for (int i = 0; i < NJOBS; i++) {
            ja.src[i] = js[i].s; ja.K[i] = js[i].K; ja.N[i] = js[i].N;
            ja.off0[i] = js[i].off0; ja.ldo[i] = js[i].ldo;
            ja.dst[i] = off; woff[i] = off;
            off += js[i].sz;
        }
    }
    long pw2off1 = woff[15] + 512L * 512;
    long pw2off2 = pw2off1 + 256L * 256;
    tw_kernel<<<dim3(256, NJOBS), dim3(256), 0, stream>>>(ja, wbuf);

    ushort* wBig5_1 = wbuf + woff[2];
    ushort* updW1   = wbuf + woff[7];
    ushort* updbT1  = wbuf + woff[8];
    ushort* wBig5_2 = wbuf + woff[9];
    ushort* updW2   = wbuf + woff[14];
    ushort* updbT2  = wbuf + woff[15];
    ushort* pw2f1   = wbuf + pw2off1;
    ushort* pw2f2   = wbuf + pw2off2;

    // ---- prep (biases, pos tables, vb, pw2 bf16, feat->bf16) ----
    {
        long tot = 1280 + 2560 + 9 * 1280 + 9 * 2560 + 9 * 256 + 9 * 512
                 + 256 + 512 + 256 * 256 + 512 * 512
                 + (long)NN * 512 / 4 + (long)NN * 1024 / 4;
        prep_kernel<<<dim3((unsigned)((tot + 255) / 256)), dim3(256), 0, stream>>>(
            (const float*)d_in[10], (const float*)d_in[14], (const float*)d_in[22],
            (const float*)d_in[24], (const float*)d_in[28], (const float*)d_in[36],
            pos_table,
            s1_pw1, s1_att, s1_skp, s2_pw1, s2_att, s2_skp,
            (const float*)d_in[12], s1_upd, (const float*)d_in[26], s2_upd,
            (const float*)d_in[11], (const float*)d_in[25],
            feat_low, feat_high,
            biasC1, biasC2, posPB1, posPB2, posU1, posU2, vb1, vb2, pw2f1, pw2f2, featB);
    }

    // ---- Wcomb = pw2 @ updb, transposed into updW G-columns ----
    mg(stream, 256, 256, 256, updbT1, 256, pw2f1, 256, 0, 0, 0, 0, updW1 + 256, 512, 1, 0);
    mg(stream, 512, 512, 512, updbT2, 512, pw2f2, 512, 0, 0, 0, 0, updW2 + 512, 1024, 1, 0);

    // ---- projections (split-K z=2, partials in PT, reduce to ixa1) ----
    mg(stream, NN, 256, 256, featB, 512, wbuf + woff[0], 512, 0, 0, 0,
       PT, 0, 256, 2, (long)NN * 256);
    mg(stream, NN, 256, 512, featB + (size_t)NN * 512, 1024, wbuf + woff[1], 1024, 0, 0, 0,
       PT + (size_t)2 * NN * 256, 0, 256, 2, (long)NN * 256);
    pjred_kernel<<<dim3(NN2 * 64 / 256), dim3(256), 0, stream>>>(PT, proj_low_b, proj_high_b, ixa1);

    // ---- stage 1 (batched, M = 18432) ----
    mg(stream, NN2, 1280, 256, ixa1, 512, wBig5_1, 256, biasC1, posPB1, 1280, 0, PB, 1280, 1, 0);
    edge_kernel<<<dim3(2 * NUM_GRAPHS), dim3(256), 0, stream>>>(
        PB, att2_w1, ixa1 + 256, 512, S, 256, 5);
    mg(stream, NN2, 256, 256, ixa1, 512, updW1, 512, 0, 0, 0, PT, 0, 256, 2, (long)NN2 * 256);
    ln_kernel<<<dim3(NN2), dim3(256), 0, stream>>>(
        PT, PT + (size_t)NN2 * 256, upd_b1, vb1, S, posU1,
        PB + 4 * 256, 1280, ln_g1, ln_b1, ixa2, 1024, NN, 0, 256);

    // ---- stage 2 ----
    mg(stream, NN, 2560, 512, ixa2, 1024, wBig5_2, 512, biasC2, posPB2, 2560, 0, PB, 2560, 1, 0);
    edge_kernel<<<dim3(NUM_GRAPHS), dim3(256), 0, stream>>>(
        PB, att2_w2, ixa2 + 512, 1024, S, 512, 6);
    mg(stream, NN, 512, 512, ixa2, 1024, updW2, 1024, 0, 0, 0, PT, 0, 512, 2, (long)NN * 512);
    ln_kernel<<<dim3(NN), dim3(256), 0, stream>>>(
        PT, PT + (size_t)NN * 512, upd_b2, vb2, S, posU2,
        PB + 4 * 512, 2560, ln_g2, ln_b2, 0, 0, 1 << 30, h2, 512);

    // ---- head ----
    head_kernel<<<dim3(NUM_GRAPHS / 4), dim3(256), 0, stream>>>(h2, cls1_w, cls1_b, cls2_w, cls2_b, out);
}